// Round 1
// baseline (128.465 us; speedup 1.0000x reference)
//
#include <hip/hip_runtime.h>
#include <math.h>

#define SS 7
#define CC 30
#define NBATCH 4096
#define NCELLS (NBATCH * 49)       // 200704
#define NSLOT 2205                 // 49 * 45  (45 = 25 k0-tail + 20 k1-tail)
#define TBL (3 * NSLOT)            // D, B, C arrays
#define MAIN_THREADS 768

// ws layout:
//   [0..6) floats at offset 0: accumulators {obj, noobj, coord, Tsum, prob, pad}
//   offset 256: partials[nparts][TBL] floats

__device__ __forceinline__ void atomAddF(float* p, float v) {
    unsafeAtomicAdd(p, v);   // ds_add_f32 / global_atomic_add_f32 on gfx950
}

__global__ __launch_bounds__(MAIN_THREADS)
void yolo_main(const float* __restrict__ y, const float* __restrict__ yh,
               float* __restrict__ acc, float* __restrict__ parts, int nparts)
{
    __shared__ float tbl[TBL];         // [3][49][45]: D | B | C
    __shared__ float scr[4][16];

    for (int i = threadIdx.x; i < TBL; i += blockDim.x) tbl[i] = 0.0f;
    __syncthreads();

    float obj = 0.0f, noobj = 0.0f, coord = 0.0f, tt = 0.0f;

    const int stride = gridDim.x * blockDim.x;
    for (int cell = blockIdx.x * blockDim.x + threadIdx.x; cell < NCELLS; cell += stride) {
        const int ij = cell % 49;
        const float2* Y2 = (const float2*)(y  + (size_t)cell * CC);
        const float2* H2 = (const float2*)(yh + (size_t)cell * CC);
        float fy[CC], fh[CC];
        #pragma unroll
        for (int i = 0; i < CC / 2; i++) {
            float2 a = Y2[i]; fy[2*i] = a.x; fy[2*i+1] = a.y;
            float2 b = H2[i]; fh[2*i] = b.x; fh[2*i+1] = b.y;
        }

        const bool m0 = (fy[0] == 1.0f);
        const bool m1 = (fy[5] == 1.0f);

        float d0 = fy[0] - fh[0]; d0 *= d0;
        float d1 = fy[5] - fh[5]; d1 *= d1;
        obj   += (m0 ? d0 : 0.0f) + (m1 ? d1 : 0.0f);
        noobj += (m0 ? 0.0f : d0) + (m1 ? 0.0f : d1);

        if (m0) {
            float a = fy[1] - fh[1], b = fy[2] - fh[2];
            float c1 = sqrtf(fy[3]) - sqrtf(fh[3]);
            float c2 = sqrtf(fy[4]) - sqrtf(fh[4]);
            coord += a*a + b*b + c1*c1 + c2*c2;
        }
        if (m1) {
            float a = fy[6] - fh[6], b = fy[7] - fh[7];
            float c1 = sqrtf(fy[8]) - sqrtf(fh[8]);
            float c2 = sqrtf(fy[9]) - sqrtf(fh[9]);
            coord += a*a + b*b + c1*c1 + c2*c2;
        }

        float* T0 = tbl + ij * 45;   // k0 slot base (D); B at +NSLOT, C at +2*NSLOT

        // k=0 only: tail channels 5..9
        #pragma unroll
        for (int c = 5; c < 10; c++) {
            if (m0) {
                float t = fy[c], e = __expf(fh[c]);
                atomAddF(&T0[c-5],           e);
                atomAddF(&T0[c-5 + NSLOT],   t * e);
                atomAddF(&T0[c-5 + 2*NSLOT], e * e);
                tt += t * t;
            }
        }
        // shared channels 10..29 (k0 tail offset c-5, k1 tail offset 25+c-10)
        #pragma unroll
        for (int c = 10; c < CC; c++) {
            if (m0 | m1) {
                float t = fy[c], e = __expf(fh[c]);
                float te = t * e, ee = e * e, t2 = t * t;
                if (m0) {
                    atomAddF(&T0[c-5],           e);
                    atomAddF(&T0[c-5 + NSLOT],   te);
                    atomAddF(&T0[c-5 + 2*NSLOT], ee);
                    tt += t2;
                }
                if (m1) {
                    atomAddF(&T0[25 + c-10],           e);
                    atomAddF(&T0[25 + c-10 + NSLOT],   te);
                    atomAddF(&T0[25 + c-10 + 2*NSLOT], ee);
                    tt += t2;
                }
            }
        }
    }

    // reduce the 4 scalar sums: wave shuffle -> LDS -> one atomic each
    const int lane = threadIdx.x & 63;
    const int wv   = threadIdx.x >> 6;
    #pragma unroll
    for (int off = 32; off > 0; off >>= 1) {
        obj   += __shfl_down(obj,   off);
        noobj += __shfl_down(noobj, off);
        coord += __shfl_down(coord, off);
        tt    += __shfl_down(tt,    off);
    }
    if (lane == 0) { scr[0][wv] = obj; scr[1][wv] = noobj; scr[2][wv] = coord; scr[3][wv] = tt; }
    __syncthreads();   // also orders tbl atomics before writeback

    // write this block's slot-table partial (no global atomics for the table)
    float* dst = parts + (size_t)blockIdx.x * TBL;
    for (int i = threadIdx.x; i < TBL; i += blockDim.x) dst[i] = tbl[i];

    if (threadIdx.x < 4) {
        const int nw = blockDim.x >> 6;
        float s = 0.0f;
        for (int w = 0; w < nw; w++) s += scr[threadIdx.x][w];
        atomAddF(&acc[threadIdx.x], s);
    }
}

__global__ __launch_bounds__(256)
void yolo_reduce(const float* __restrict__ parts, float* __restrict__ acc, int nparts)
{
    const int s = blockIdx.x * 256 + threadIdx.x;
    double contrib = 0.0;
    if (s < NSLOT) {
        double D = 0.0, B = 0.0, Cx = 0.0;
        const float* p = parts + s;
        #pragma unroll 4
        for (int q = 0; q < nparts; q++) {
            D  += (double)p[0];
            B  += (double)p[NSLOT];
            Cx += (double)p[2*NSLOT];
            p  += TBL;
        }
        if (D > 0.0) {
            double inv = 1.0 / D;
            contrib = Cx * inv * inv - 2.0 * B * inv;
        }
    }
    __shared__ double sd[256];
    sd[threadIdx.x] = contrib;
    __syncthreads();
    for (int off = 128; off > 0; off >>= 1) {
        if (threadIdx.x < off) sd[threadIdx.x] += sd[threadIdx.x + off];
        __syncthreads();
    }
    if (threadIdx.x == 0) atomAddF(&acc[4], (float)sd[0]);
}

__global__ void yolo_final(const float* __restrict__ acc, float* __restrict__ out)
{
    // loss = (obj + 0.5*noobj + 5*coord + (Tsum + prob_extra)) / BATCH
    double loss = (double)acc[0] + 0.5 * (double)acc[1] + 5.0 * (double)acc[2]
                + (double)acc[3] + (double)acc[4];
    out[0] = (float)(loss / (double)NBATCH);
}

extern "C" void kernel_launch(void* const* d_in, const int* in_sizes, int n_in,
                              void* d_out, int out_size, void* d_ws, size_t ws_size,
                              hipStream_t stream)
{
    const float* y  = (const float*)d_in[0];
    const float* yh = (const float*)d_in[1];
    float* out   = (float*)d_out;
    float* acc   = (float*)d_ws;
    float* parts = (float*)((char*)d_ws + 256);

    const size_t per_part = (size_t)TBL * sizeof(float);
    int maxparts = (ws_size > 256) ? (int)((ws_size - 256) / per_part) : 1;
    if (maxparts < 1) maxparts = 1;
    int nblocks = maxparts < 256 ? maxparts : 256;

    hipMemsetAsync(d_ws, 0, 64, stream);   // zero the 5 scalar accumulators
    yolo_main<<<nblocks, MAIN_THREADS, 0, stream>>>(y, yh, acc, parts, nblocks);
    yolo_reduce<<<(NSLOT + 255) / 256, 256, 0, stream>>>(parts, acc, nblocks);
    yolo_final<<<1, 1, 0, stream>>>(acc, out);
}

// Round 4
// 67.903 us; speedup vs baseline: 1.8919x; 1.8919x over previous
//
#include <hip/hip_runtime.h>
#include <math.h>

#define CC 30
#define NBATCH 4096
#define NIJ 49
#define NPAIR 1225            // 49 ij * 25 tail channels (c = 5..29)
#define THREADS 512

// ws layout:
//   [0..64) bytes: accumulators {obj, noobj, coord, tt, prob_extra}
//   offset 1024: partials, layout [6 cats][NPAIR slots][nwg], floats

__device__ __forceinline__ void atomAddF(float* p, float v) { unsafeAtomicAdd(p, v); }

__global__ __launch_bounds__(THREADS)
void yolo_main(const float* __restrict__ y, const float* __restrict__ yh,
               float* __restrict__ acc, float* __restrict__ parts, int nwg)
{
    __shared__ float tY[4 * 1470];       // 4 batches of raw y   (23.5 KB)
    __shared__ float tH[4 * 1470];       // 4 batches of raw y_h (23.5 KB)
    __shared__ float scr[4][8];

    const int tid = threadIdx.x;
    const int wg  = blockIdx.x;
    const int bpw = NBATCH / nwg;        // batches per wg (multiple of 4)
    const int nslab = bpw >> 2;

    // fixed (ij, channel) slot ownership
    int  ijv[3], cv[3], pr[3];
    bool val[3];
    #pragma unroll
    for (int i = 0; i < 3; i++) {
        int p = tid + i * THREADS;
        val[i] = (p < NPAIR);
        pr[i]  = p;
        int pp = val[i] ? p : 0;
        ijv[i] = pp / 25;
        cv[i]  = 5 + pp % 25;
    }

    float D0[3] = {0,0,0}, B0[3] = {0,0,0}, C0[3] = {0,0,0};
    float D1[3] = {0,0,0}, B1[3] = {0,0,0}, C1[3] = {0,0,0};
    float obj = 0.f, noobj = 0.f, coord = 0.f, tt = 0.f;

    for (int s = 0; s < nslab; s++) {
        const int b0 = wg * bpw + s * 4;                 // multiple of 4
        const size_t f4 = (size_t)b0 * 1470 / 4;         // exact (b0 even)
        const float4* Y4 = (const float4*)y  + f4;
        const float4* H4 = (const float4*)yh + f4;
        float4* tY4 = (float4*)tY;
        float4* tH4 = (float4*)tH;
        #pragma unroll 3
        for (int i = tid; i < 1470; i += THREADS) { tY4[i] = Y4[i]; tH4[i] = H4[i]; }
        __syncthreads();

        // ---- pointwise part: 196 cells in this slab ----
        if (tid < 4 * NIJ) {
            const int base = tid * CC;                   // b*1470 + ij*30
            float y0 = tY[base],     h0 = tH[base];
            float y5 = tY[base + 5], h5 = tH[base + 5];
            float d0 = y0 - h0; d0 *= d0;
            float d5 = y5 - h5; d5 *= d5;
            const bool m0 = (y0 == 1.0f), m1 = (y5 == 1.0f);
            obj   += (m0 ? d0 : 0.f) + (m1 ? d5 : 0.f);
            noobj += (m0 ? 0.f : d0) + (m1 ? 0.f : d5);
            if (m0) {
                float a  = tY[base + 1] - tH[base + 1];
                float b2 = tY[base + 2] - tH[base + 2];
                float c1 = sqrtf(tY[base + 3]) - sqrtf(tH[base + 3]);
                float c2 = sqrtf(tY[base + 4]) - sqrtf(tH[base + 4]);
                coord += a * a + b2 * b2 + c1 * c1 + c2 * c2;
            }
            if (m1) {
                float a  = tY[base + 6] - tH[base + 6];
                float b2 = tY[base + 7] - tH[base + 7];
                float c1 = sqrtf(tY[base + 8]) - sqrtf(tH[base + 8]);
                float c2 = sqrtf(tY[base + 9]) - sqrtf(tH[base + 9]);
                coord += a * a + b2 * b2 + c1 * c1 + c2 * c2;
            }
        }

        // ---- slot phase: register accumulation, no atomics ----
        #pragma unroll
        for (int b = 0; b < 4; b++) {
            #pragma unroll
            for (int i = 0; i < 3; i++) {
                if (!val[i]) continue;
                const int cb = b * 1470 + ijv[i] * CC;
                const float w0 = (tY[cb] == 1.0f) ? 1.f : 0.f;
                const float w1 = (cv[i] >= 10 && tY[cb + 5] == 1.0f) ? 1.f : 0.f;
                const float t  = tY[cb + cv[i]];
                const float th = tH[cb + cv[i]];
                const float e  = __expf(th);
                const float te = t * e, ee = e * e, t2 = t * t;
                D0[i] = fmaf(e,  w0, D0[i]);
                B0[i] = fmaf(te, w0, B0[i]);
                C0[i] = fmaf(ee, w0, C0[i]);
                D1[i] = fmaf(e,  w1, D1[i]);
                B1[i] = fmaf(te, w1, B1[i]);
                C1[i] = fmaf(ee, w1, C1[i]);
                tt = fmaf(t2, w0 + w1, tt);
            }
        }
        __syncthreads();   // protect LDS before next slab load
    }

    // ---- write per-wg slot partials (coalesced-for-reduce layout) ----
    const size_t sl = (size_t)NPAIR * nwg;
    #pragma unroll
    for (int i = 0; i < 3; i++) {
        if (!val[i]) continue;
        float* pp = parts + (size_t)pr[i] * nwg + wg;
        pp[0]      = D0[i];
        pp[sl]     = B0[i];
        pp[2 * sl] = C0[i];
        if (cv[i] >= 10) {
            pp[3 * sl] = D1[i];
            pp[4 * sl] = B1[i];
            pp[5 * sl] = C1[i];
        }
    }

    // ---- scalar reduction: shuffle -> LDS -> 4 atomics ----
    const int lane = tid & 63, wv = tid >> 6;
    #pragma unroll
    for (int off = 32; off > 0; off >>= 1) {
        obj   += __shfl_down(obj,   off);
        noobj += __shfl_down(noobj, off);
        coord += __shfl_down(coord, off);
        tt    += __shfl_down(tt,    off);
    }
    if (lane == 0) { scr[0][wv] = obj; scr[1][wv] = noobj; scr[2][wv] = coord; scr[3][wv] = tt; }
    __syncthreads();
    if (tid < 4) {
        float sacc = 0.f;
        #pragma unroll
        for (int w = 0; w < THREADS / 64; w++) sacc += scr[tid][w];
        atomAddF(&acc[tid], sacc);
    }
}

__global__ __launch_bounds__(256)
void yolo_reduce(const float* __restrict__ parts, float* __restrict__ acc, int nwg)
{
    const int s = blockIdx.x;            // slot 0..1224
    const int cidx = s % 25;             // channel = 5 + cidx
    const size_t sl = (size_t)NPAIR * nwg;
    const float* base = parts + (size_t)s * nwg;

    float v0 = 0, v1 = 0, v2 = 0, v3 = 0, v4 = 0, v5 = 0;
    for (int wg = threadIdx.x; wg < nwg; wg += 256) {
        v0 += base[wg];
        v1 += base[sl + wg];
        v2 += base[2 * sl + wg];
        if (cidx >= 5) {
            v3 += base[3 * sl + wg];
            v4 += base[4 * sl + wg];
            v5 += base[5 * sl + wg];
        }
    }
    #pragma unroll
    for (int off = 32; off > 0; off >>= 1) {
        v0 += __shfl_down(v0, off); v1 += __shfl_down(v1, off);
        v2 += __shfl_down(v2, off); v3 += __shfl_down(v3, off);
        v4 += __shfl_down(v4, off); v5 += __shfl_down(v5, off);
    }
    __shared__ float red[4][6];
    const int lane = threadIdx.x & 63, wv = threadIdx.x >> 6;
    if (lane == 0) {
        red[wv][0] = v0; red[wv][1] = v1; red[wv][2] = v2;
        red[wv][3] = v3; red[wv][4] = v4; red[wv][5] = v5;
    }
    __syncthreads();
    if (threadIdx.x == 0) {
        float D0 = 0, B0 = 0, C0 = 0, D1 = 0, B1 = 0, C1 = 0;
        #pragma unroll
        for (int w = 0; w < 4; w++) {
            D0 += red[w][0]; B0 += red[w][1]; C0 += red[w][2];
            D1 += red[w][3]; B1 += red[w][4]; C1 += red[w][5];
        }
        float contrib = 0.f;
        if (D0 > 0.f) contrib += C0 / (D0 * D0) - 2.f * B0 / D0;
        if (cidx >= 5 && D1 > 0.f) contrib += C1 / (D1 * D1) - 2.f * B1 / D1;
        atomAddF(&acc[4], contrib);
    }
}

__global__ void yolo_final(const float* __restrict__ acc, float* __restrict__ out)
{
    double loss = (double)acc[0] + 0.5 * (double)acc[1] + 5.0 * (double)acc[2]
                + (double)acc[3] + (double)acc[4];
    out[0] = (float)(loss / (double)NBATCH);
}

extern "C" void kernel_launch(void* const* d_in, const int* in_sizes, int n_in,
                              void* d_out, int out_size, void* d_ws, size_t ws_size,
                              hipStream_t stream)
{
    const float* y  = (const float*)d_in[0];
    const float* yh = (const float*)d_in[1];
    float* out   = (float*)d_out;
    float* acc   = (float*)d_ws;
    float* parts = (float*)((char*)d_ws + 1024);

    int nwg = 64;
    const size_t per_wg = (size_t)NPAIR * 6 * sizeof(float);   // 29.4 KB
    if (ws_size >= 1024 + 512 * per_wg) nwg = 512;
    else if (ws_size >= 1024 + 256 * per_wg) nwg = 256;
    else if (ws_size >= 1024 + 128 * per_wg) nwg = 128;

    hipMemsetAsync(d_ws, 0, 64, stream);
    yolo_main<<<nwg, THREADS, 0, stream>>>(y, yh, acc, parts, nwg);
    yolo_reduce<<<NPAIR, 256, 0, stream>>>(parts, acc, nwg);
    yolo_final<<<1, 1, 0, stream>>>(acc, out);
}

// Round 5
// 39.540 us; speedup vs baseline: 3.2490x; 1.7173x over previous
//
#include <hip/hip_runtime.h>
#include <math.h>

#define CC 30
#define NBATCH 4096
#define NIJ 49
#define NPAIR 1225            // 49 ij * 25 tail channels (c = 5..29)
#define NSLOT6 7350           // 6 categories * NPAIR
#define THREADS 512

// ws layout:
//   offset 0     : acc[5] {obj, noobj, coord, tt, (unused)}
//   offset 1024  : tbl[7350] summed slot table (zeroed each call)
//   offset 33792 : parts[nwg][7350]  (contiguous 29.4 KB per wg)

__device__ __forceinline__ void atomAddF(float* p, float v) { unsafeAtomicAdd(p, v); }

__global__ __launch_bounds__(THREADS)
void yolo_main(const float* __restrict__ y, const float* __restrict__ yh,
               float* __restrict__ acc, float* __restrict__ parts, int nwg)
{
    __shared__ float tY[4 * 1470];       // 4 batches of raw y   (23.5 KB)
    __shared__ float tH[4 * 1470];       // 4 batches of raw y_h (23.5 KB)
    __shared__ float scr[4][8];

    const int tid = threadIdx.x;
    const int wg  = blockIdx.x;
    const int bpw = NBATCH / nwg;        // batches per wg (multiple of 4)
    const int nslab = bpw >> 2;

    // fixed (ij, channel) slot ownership
    int  ijv[3], cv[3], pr[3];
    bool val[3];
    #pragma unroll
    for (int i = 0; i < 3; i++) {
        int p = tid + i * THREADS;
        val[i] = (p < NPAIR);
        pr[i]  = p;
        int pp = val[i] ? p : 0;
        ijv[i] = pp / 25;
        cv[i]  = 5 + pp % 25;
    }

    float D0[3] = {0,0,0}, B0[3] = {0,0,0}, C0[3] = {0,0,0};
    float D1[3] = {0,0,0}, B1[3] = {0,0,0}, C1[3] = {0,0,0};
    float obj = 0.f, noobj = 0.f, coord = 0.f, tt = 0.f;

    for (int s = 0; s < nslab; s++) {
        const int b0 = wg * bpw + s * 4;                 // multiple of 4
        const size_t f4 = (size_t)b0 * 1470 / 4;         // exact (b0 even)
        const float4* Y4 = (const float4*)y  + f4;
        const float4* H4 = (const float4*)yh + f4;
        float4* tY4 = (float4*)tY;
        float4* tH4 = (float4*)tH;
        #pragma unroll 3
        for (int i = tid; i < 1470; i += THREADS) { tY4[i] = Y4[i]; tH4[i] = H4[i]; }
        __syncthreads();

        // ---- pointwise part: 196 cells in this slab ----
        if (tid < 4 * NIJ) {
            const int base = tid * CC;                   // b*1470 + ij*30
            float y0 = tY[base],     h0 = tH[base];
            float y5 = tY[base + 5], h5 = tH[base + 5];
            float d0 = y0 - h0; d0 *= d0;
            float d5 = y5 - h5; d5 *= d5;
            const bool m0 = (y0 == 1.0f), m1 = (y5 == 1.0f);
            obj   += (m0 ? d0 : 0.f) + (m1 ? d5 : 0.f);
            noobj += (m0 ? 0.f : d0) + (m1 ? 0.f : d5);
            if (m0) {
                float a  = tY[base + 1] - tH[base + 1];
                float b2 = tY[base + 2] - tH[base + 2];
                float c1 = sqrtf(tY[base + 3]) - sqrtf(tH[base + 3]);
                float c2 = sqrtf(tY[base + 4]) - sqrtf(tH[base + 4]);
                coord += a * a + b2 * b2 + c1 * c1 + c2 * c2;
            }
            if (m1) {
                float a  = tY[base + 6] - tH[base + 6];
                float b2 = tY[base + 7] - tH[base + 7];
                float c1 = sqrtf(tY[base + 8]) - sqrtf(tH[base + 8]);
                float c2 = sqrtf(tY[base + 9]) - sqrtf(tH[base + 9]);
                coord += a * a + b2 * b2 + c1 * c1 + c2 * c2;
            }
        }

        // ---- slot phase: register accumulation, no atomics ----
        #pragma unroll
        for (int b = 0; b < 4; b++) {
            #pragma unroll
            for (int i = 0; i < 3; i++) {
                if (!val[i]) continue;
                const int cb = b * 1470 + ijv[i] * CC;
                const float w0 = (tY[cb] == 1.0f) ? 1.f : 0.f;
                const float w1 = (cv[i] >= 10 && tY[cb + 5] == 1.0f) ? 1.f : 0.f;
                const float t  = tY[cb + cv[i]];
                const float th = tH[cb + cv[i]];
                const float e  = __expf(th);
                const float te = t * e, ee = e * e, t2 = t * t;
                D0[i] = fmaf(e,  w0, D0[i]);
                B0[i] = fmaf(te, w0, B0[i]);
                C0[i] = fmaf(ee, w0, C0[i]);
                D1[i] = fmaf(e,  w1, D1[i]);
                B1[i] = fmaf(te, w1, B1[i]);
                C1[i] = fmaf(ee, w1, C1[i]);
                tt = fmaf(t2, w0 + w1, tt);
            }
        }
        __syncthreads();   // protect LDS before next slab load
    }

    // ---- per-wg partials: contiguous block, coalesced stores ----
    float* pp = parts + (size_t)wg * NSLOT6;
    #pragma unroll
    for (int i = 0; i < 3; i++) {
        if (!val[i]) continue;
        const int p = pr[i];
        pp[p]            = D0[i];
        pp[NPAIR + p]    = B0[i];
        pp[2*NPAIR + p]  = C0[i];
        pp[3*NPAIR + p]  = D1[i];   // zero when cv<10 (w1 never set)
        pp[4*NPAIR + p]  = B1[i];
        pp[5*NPAIR + p]  = C1[i];
    }

    // ---- scalar reduction: shuffle -> LDS -> 4 atomics ----
    const int lane = tid & 63, wv = tid >> 6;
    #pragma unroll
    for (int off = 32; off > 0; off >>= 1) {
        obj   += __shfl_down(obj,   off);
        noobj += __shfl_down(noobj, off);
        coord += __shfl_down(coord, off);
        tt    += __shfl_down(tt,    off);
    }
    if (lane == 0) { scr[0][wv] = obj; scr[1][wv] = noobj; scr[2][wv] = coord; scr[3][wv] = tt; }
    __syncthreads();
    if (tid < 4) {
        float sacc = 0.f;
        #pragma unroll
        for (int w = 0; w < THREADS / 64; w++) sacc += scr[tid][w];
        atomAddF(&acc[tid], sacc);
    }
}

// grid (29, chunks): block (bx, ch) sums wgs [ch*per, (ch+1)*per) for 256 slots,
// coalesced reads, one 8-way-contended atomic per (cat,slot).
__global__ __launch_bounds__(256)
void yolo_reduce(const float* __restrict__ parts, float* __restrict__ tbl,
                 int nwg, int chunks)
{
    const int p = blockIdx.x * 256 + threadIdx.x;
    if (p >= NSLOT6) return;
    const int per = nwg / chunks;
    const float* q = parts + (size_t)(blockIdx.y * per) * NSLOT6 + p;
    float s = 0.f;
    #pragma unroll 4
    for (int w = 0; w < per; ++w) { s += *q; q += NSLOT6; }
    atomAddF(&tbl[p], s);
}

__global__ __launch_bounds__(1024)
void yolo_final(const float* __restrict__ tbl, const float* __restrict__ acc,
                float* __restrict__ out)
{
    float c = 0.f;
    for (int s = threadIdx.x; s < NPAIR; s += 1024) {
        const int cidx = s % 25;
        float D0 = tbl[s], B0 = tbl[NPAIR + s], C0 = tbl[2*NPAIR + s];
        if (D0 > 0.f) c += C0 / (D0 * D0) - 2.f * B0 / D0;
        if (cidx >= 5) {
            float D1 = tbl[3*NPAIR + s], B1 = tbl[4*NPAIR + s], C1 = tbl[5*NPAIR + s];
            if (D1 > 0.f) c += C1 / (D1 * D1) - 2.f * B1 / D1;
        }
    }
    __shared__ float sred[16];
    #pragma unroll
    for (int off = 32; off > 0; off >>= 1) c += __shfl_down(c, off);
    const int lane = threadIdx.x & 63, wv = threadIdx.x >> 6;
    if (lane == 0) sred[wv] = c;
    __syncthreads();
    if (threadIdx.x == 0) {
        float ct = 0.f;
        #pragma unroll
        for (int w = 0; w < 16; w++) ct += sred[w];
        double loss = (double)acc[0] + 0.5 * (double)acc[1] + 5.0 * (double)acc[2]
                    + (double)acc[3] + (double)ct;
        out[0] = (float)(loss / (double)NBATCH);
    }
}

extern "C" void kernel_launch(void* const* d_in, const int* in_sizes, int n_in,
                              void* d_out, int out_size, void* d_ws, size_t ws_size,
                              hipStream_t stream)
{
    const float* y  = (const float*)d_in[0];
    const float* yh = (const float*)d_in[1];
    float* out   = (float*)d_out;
    float* acc   = (float*)d_ws;
    float* tbl   = (float*)((char*)d_ws + 1024);
    float* parts = (float*)((char*)d_ws + 33792);

    const size_t per_wg = (size_t)NSLOT6 * sizeof(float);   // 29.4 KB
    int nwg, chunks;
    if      (ws_size >= 33792 + 512 * per_wg) { nwg = 512; chunks = 8; }
    else if (ws_size >= 33792 + 256 * per_wg) { nwg = 256; chunks = 8; }
    else if (ws_size >= 33792 + 128 * per_wg) { nwg = 128; chunks = 4; }
    else                                      { nwg = 64;  chunks = 4; }

    hipMemsetAsync(d_ws, 0, 33792, stream);   // zero acc + tbl
    yolo_main<<<nwg, THREADS, 0, stream>>>(y, yh, acc, parts, nwg);
    dim3 g2((NSLOT6 + 255) / 256, chunks);
    yolo_reduce<<<g2, 256, 0, stream>>>(parts, tbl, nwg, chunks);
    yolo_final<<<1, 1024, 0, stream>>>(tbl, acc, out);
}

// Round 6
// 31.593 us; speedup vs baseline: 4.0663x; 1.2516x over previous
//
#include <hip/hip_runtime.h>
#include <math.h>

#define CC 30
#define NBATCH 4096
#define NIJ 49
#define NPAIR 1225            // 49 ij * 25 tail channels (c = 5..29)
#define NSLOT6 7350           // 6 categories * NPAIR
#define THREADS 512

// ws layout (NO initialization required — every read location is written first):
//   offset 0     : tbl[7350]            (written by yolo_reduce)
//   offset 29696 : scal[nwg][4]         (written by yolo_main)
//   offset 38912 : parts[nwg][7350]     (written by yolo_main)

__global__ __launch_bounds__(THREADS)
void yolo_main(const float* __restrict__ y, const float* __restrict__ yh,
               float* __restrict__ scal, float* __restrict__ parts, int nwg)
{
    __shared__ float tY[4 * 1470];       // 4 batches of raw y   (23.5 KB)
    __shared__ float tH[4 * 1470];       // 4 batches of raw y_h (23.5 KB)
    __shared__ float scr[4][8];

    const int tid = threadIdx.x;
    const int wg  = blockIdx.x;
    const int bpw = NBATCH / nwg;        // batches per wg (multiple of 4)
    const int nslab = bpw >> 2;

    // fixed (ij, channel) slot ownership
    int  ijv[3], cv[3], pr[3];
    bool val[3];
    #pragma unroll
    for (int i = 0; i < 3; i++) {
        int p = tid + i * THREADS;
        val[i] = (p < NPAIR);
        pr[i]  = p;
        int pp = val[i] ? p : 0;
        ijv[i] = pp / 25;
        cv[i]  = 5 + pp % 25;
    }

    float D0[3] = {0,0,0}, B0[3] = {0,0,0}, C0[3] = {0,0,0};
    float D1[3] = {0,0,0}, B1[3] = {0,0,0}, C1[3] = {0,0,0};
    float obj = 0.f, noobj = 0.f, coord = 0.f, tt = 0.f;

    for (int s = 0; s < nslab; s++) {
        const int b0 = wg * bpw + s * 4;                 // multiple of 4
        const size_t f4 = (size_t)b0 * 1470 / 4;         // exact (b0 even)
        const float4* Y4 = (const float4*)y  + f4;
        const float4* H4 = (const float4*)yh + f4;
        float4* tY4 = (float4*)tY;
        float4* tH4 = (float4*)tH;
        #pragma unroll 3
        for (int i = tid; i < 1470; i += THREADS) { tY4[i] = Y4[i]; tH4[i] = H4[i]; }
        __syncthreads();

        // ---- pointwise part: 196 cells in this slab ----
        if (tid < 4 * NIJ) {
            const int base = tid * CC;                   // b*1470 + ij*30
            float y0 = tY[base],     h0 = tH[base];
            float y5 = tY[base + 5], h5 = tH[base + 5];
            float d0 = y0 - h0; d0 *= d0;
            float d5 = y5 - h5; d5 *= d5;
            const bool m0 = (y0 == 1.0f), m1 = (y5 == 1.0f);
            obj   += (m0 ? d0 : 0.f) + (m1 ? d5 : 0.f);
            noobj += (m0 ? 0.f : d0) + (m1 ? 0.f : d5);
            if (m0) {
                float a  = tY[base + 1] - tH[base + 1];
                float b2 = tY[base + 2] - tH[base + 2];
                float c1 = sqrtf(tY[base + 3]) - sqrtf(tH[base + 3]);
                float c2 = sqrtf(tY[base + 4]) - sqrtf(tH[base + 4]);
                coord += a * a + b2 * b2 + c1 * c1 + c2 * c2;
            }
            if (m1) {
                float a  = tY[base + 6] - tH[base + 6];
                float b2 = tY[base + 7] - tH[base + 7];
                float c1 = sqrtf(tY[base + 8]) - sqrtf(tH[base + 8]);
                float c2 = sqrtf(tY[base + 9]) - sqrtf(tH[base + 9]);
                coord += a * a + b2 * b2 + c1 * c1 + c2 * c2;
            }
        }

        // ---- slot phase: register accumulation, no atomics ----
        #pragma unroll
        for (int b = 0; b < 4; b++) {
            #pragma unroll
            for (int i = 0; i < 3; i++) {
                if (!val[i]) continue;
                const int cb = b * 1470 + ijv[i] * CC;
                const float w0 = (tY[cb] == 1.0f) ? 1.f : 0.f;
                const float w1 = (cv[i] >= 10 && tY[cb + 5] == 1.0f) ? 1.f : 0.f;
                const float t  = tY[cb + cv[i]];
                const float th = tH[cb + cv[i]];
                const float e  = __expf(th);
                const float te = t * e, ee = e * e, t2 = t * t;
                D0[i] = fmaf(e,  w0, D0[i]);
                B0[i] = fmaf(te, w0, B0[i]);
                C0[i] = fmaf(ee, w0, C0[i]);
                D1[i] = fmaf(e,  w1, D1[i]);
                B1[i] = fmaf(te, w1, B1[i]);
                C1[i] = fmaf(ee, w1, C1[i]);
                tt = fmaf(t2, w0 + w1, tt);
            }
        }
        __syncthreads();   // protect LDS before next slab load
    }

    // ---- per-wg partials: contiguous block, coalesced stores ----
    float* pp = parts + (size_t)wg * NSLOT6;
    #pragma unroll
    for (int i = 0; i < 3; i++) {
        if (!val[i]) continue;
        const int p = pr[i];
        pp[p]            = D0[i];
        pp[NPAIR + p]    = B0[i];
        pp[2*NPAIR + p]  = C0[i];
        pp[3*NPAIR + p]  = D1[i];   // zero when cv<10 (w1 never set)
        pp[4*NPAIR + p]  = B1[i];
        pp[5*NPAIR + p]  = C1[i];
    }

    // ---- scalar sums: shuffle -> LDS -> one float4 store per wg ----
    const int lane = tid & 63, wv = tid >> 6;
    #pragma unroll
    for (int off = 32; off > 0; off >>= 1) {
        obj   += __shfl_down(obj,   off);
        noobj += __shfl_down(noobj, off);
        coord += __shfl_down(coord, off);
        tt    += __shfl_down(tt,    off);
    }
    if (lane == 0) { scr[0][wv] = obj; scr[1][wv] = noobj; scr[2][wv] = coord; scr[3][wv] = tt; }
    __syncthreads();
    if (tid < 4) {
        float sacc = 0.f;
        #pragma unroll
        for (int w = 0; w < THREADS / 64; w++) sacc += scr[tid][w];
        scal[wg * 4 + tid] = sacc;
    }
}

// 58 blocks x 1024 threads: block owns 128 p-slots, 8 wg-chunks per slot,
// fully coalesced reads, LDS chunk-reduce, plain (non-atomic) store.
__global__ __launch_bounds__(1024)
void yolo_reduce(const float* __restrict__ parts, float* __restrict__ tbl, int nwg)
{
    const int pl = threadIdx.x & 127;
    const int ch = threadIdx.x >> 7;            // 0..7
    const int p  = blockIdx.x * 128 + pl;
    const int per = nwg >> 3;                   // nwg/8
    float s = 0.f;
    if (p < NSLOT6) {
        const float* q = parts + (size_t)(ch * per) * NSLOT6 + p;
        #pragma unroll 4
        for (int w = 0; w < per; ++w) { s += *q; q += NSLOT6; }
    }
    __shared__ float sred[8][128];
    sred[ch][pl] = s;
    __syncthreads();
    if (threadIdx.x < 128) {
        const int pp = blockIdx.x * 128 + threadIdx.x;
        if (pp < NSLOT6) {
            float t = 0.f;
            #pragma unroll
            for (int c = 0; c < 8; c++) t += sred[c][threadIdx.x];
            tbl[pp] = t;
        }
    }
}

__global__ __launch_bounds__(1024)
void yolo_final(const float* __restrict__ tbl, const float* __restrict__ scal,
                float* __restrict__ out, int nwg)
{
    float v = 0.f;

    // prob term: per-slot contribution from the summed table
    for (int s = threadIdx.x; s < NPAIR; s += 1024) {
        const int cidx = s % 25;
        float D0 = tbl[s], B0 = tbl[NPAIR + s], C0 = tbl[2*NPAIR + s];
        if (D0 > 0.f) v += C0 / (D0 * D0) - 2.f * B0 / D0;
        if (cidx >= 5) {
            float D1 = tbl[3*NPAIR + s], B1 = tbl[4*NPAIR + s], C1 = tbl[5*NPAIR + s];
            if (D1 > 0.f) v += C1 / (D1 * D1) - 2.f * B1 / D1;
        }
    }

    // scalar terms: weights commute with the sum
    const float4* s4 = (const float4*)scal;
    for (int w = threadIdx.x; w < nwg; w += 1024) {
        float4 a = s4[w];
        v += a.x + 0.5f * a.y + 5.0f * a.z + a.w;
    }

    __shared__ float sred[16];
    #pragma unroll
    for (int off = 32; off > 0; off >>= 1) v += __shfl_down(v, off);
    const int lane = threadIdx.x & 63, wv = threadIdx.x >> 6;
    if (lane == 0) sred[wv] = v;
    __syncthreads();
    if (threadIdx.x == 0) {
        float tot = 0.f;
        #pragma unroll
        for (int w = 0; w < 16; w++) tot += sred[w];
        out[0] = tot / (float)NBATCH;
    }
}

extern "C" void kernel_launch(void* const* d_in, const int* in_sizes, int n_in,
                              void* d_out, int out_size, void* d_ws, size_t ws_size,
                              hipStream_t stream)
{
    const float* y  = (const float*)d_in[0];
    const float* yh = (const float*)d_in[1];
    float* out   = (float*)d_out;
    float* tbl   = (float*)d_ws;
    float* scal  = (float*)((char*)d_ws + 29696);
    float* parts = (float*)((char*)d_ws + 38912);

    const size_t per_wg = (size_t)NSLOT6 * sizeof(float);   // 29.4 KB
    int nwg;
    if      (ws_size >= 38912 + 512 * per_wg) nwg = 512;
    else if (ws_size >= 38912 + 256 * per_wg) nwg = 256;
    else if (ws_size >= 38912 + 128 * per_wg) nwg = 128;
    else                                      nwg = 64;

    yolo_main<<<nwg, THREADS, 0, stream>>>(y, yh, scal, parts, nwg);
    yolo_reduce<<<(NSLOT6 + 127) / 128, 1024, 0, stream>>>(parts, tbl, nwg);
    yolo_final<<<1, 1024, 0, stream>>>(tbl, scal, out, nwg);
}

// Round 7
// 27.873 us; speedup vs baseline: 4.6089x; 1.1335x over previous
//
#include <hip/hip_runtime.h>
#include <math.h>

#define CC 30
#define NBATCH 4096
#define NIJ 49
#define NPAIR 1225            // 49 ij * 25 tail channels (c = 5..29)
#define PSTR 7352             // per-wg partial stride in floats (6*NPAIR=7350, padded to /4)
#define THREADS 512
#define SLABF4 1470           // float4 count of a 4-batch slab (4*1470 floats)

// ws layout (NO initialization required — every read location is written first):
//   offset 0      : scal[nwg][4]        (written by yolo_main)
//   offset 4096   : parts2[8][PSTR]     (written by yolo_reduce)
//   offset 239616 : parts[nwg][PSTR]    (written by yolo_main)

__global__ __launch_bounds__(THREADS)
void yolo_main(const float* __restrict__ y, const float* __restrict__ yh,
               float* __restrict__ scal, float* __restrict__ parts, int nwg)
{
    __shared__ float tY[4 * 1470];       // 4 batches of raw y   (23.5 KB)
    __shared__ float tH[4 * 1470];       // 4 batches of raw y_h (23.5 KB)
    __shared__ float scr[4][8];

    const int tid = threadIdx.x;
    const int wg  = blockIdx.x;
    const int bpw = NBATCH / nwg;        // batches per wg (multiple of 4)
    const int nslab = bpw >> 2;

    // per-thread staging indices (3 float4 per array; last partially masked)
    const int i0 = tid, i1 = tid + 512;
    const int i2r = tid + 1024;
    const int i2  = (i2r < SLABF4) ? i2r : (SLABF4 - 1);
    const bool w2 = (i2r < SLABF4);

    // fixed (ij, channel) slot ownership
    int  ijv[3], cv[3], pr[3];
    bool val[3];
    #pragma unroll
    for (int i = 0; i < 3; i++) {
        int p = tid + i * THREADS;
        val[i] = (p < NPAIR);
        pr[i]  = p;
        int pp = val[i] ? p : 0;
        ijv[i] = pp / 25;
        cv[i]  = 5 + pp % 25;
    }

    float D0[3] = {0,0,0}, B0[3] = {0,0,0}, C0[3] = {0,0,0};
    float D1[3] = {0,0,0}, B1[3] = {0,0,0}, C1[3] = {0,0,0};
    float obj = 0.f, noobj = 0.f, coord = 0.f, tt = 0.f;

    const float4* Yg = (const float4*)y;
    const float4* Hg = (const float4*)yh;
    float4* tY4 = (float4*)tY;
    float4* tH4 = (float4*)tH;

    // prologue: stage slab 0
    {
        const size_t f4 = (size_t)((wg * bpw) >> 2) * SLABF4;
        float4 a0 = Yg[f4+i0], a1 = Yg[f4+i1], a2 = Yg[f4+i2];
        float4 b0 = Hg[f4+i0], b1 = Hg[f4+i1], b2 = Hg[f4+i2];
        tY4[i0] = a0; tY4[i1] = a1; if (w2) tY4[i2] = a2;
        tH4[i0] = b0; tH4[i1] = b1; if (w2) tH4[i2] = b2;
    }
    __syncthreads();

    float4 ry0, ry1, ry2, rh0, rh1, rh2;

    for (int s = 0; s < nslab; s++) {
        // issue next slab's loads early — they fly during compute (T14)
        if (s + 1 < nslab) {
            const size_t nf4 = (size_t)((wg * bpw + (s+1)*4) >> 2) * SLABF4;
            ry0 = Yg[nf4+i0]; ry1 = Yg[nf4+i1]; ry2 = Yg[nf4+i2];
            rh0 = Hg[nf4+i0]; rh1 = Hg[nf4+i1]; rh2 = Hg[nf4+i2];
        }

        // ---- pointwise part: 196 cells in this slab ----
        if (tid < 4 * NIJ) {
            const int base = tid * CC;                   // b*1470 + ij*30
            float y0 = tY[base],     h0 = tH[base];
            float y5 = tY[base + 5], h5 = tH[base + 5];
            float d0 = y0 - h0; d0 *= d0;
            float d5 = y5 - h5; d5 *= d5;
            const bool m0 = (y0 == 1.0f), m1 = (y5 == 1.0f);
            obj   += (m0 ? d0 : 0.f) + (m1 ? d5 : 0.f);
            noobj += (m0 ? 0.f : d0) + (m1 ? 0.f : d5);
            if (m0) {
                float a  = tY[base + 1] - tH[base + 1];
                float b2 = tY[base + 2] - tH[base + 2];
                float c1 = sqrtf(tY[base + 3]) - sqrtf(tH[base + 3]);
                float c2 = sqrtf(tY[base + 4]) - sqrtf(tH[base + 4]);
                coord += a * a + b2 * b2 + c1 * c1 + c2 * c2;
            }
            if (m1) {
                float a  = tY[base + 6] - tH[base + 6];
                float b2 = tY[base + 7] - tH[base + 7];
                float c1 = sqrtf(tY[base + 8]) - sqrtf(tH[base + 8]);
                float c2 = sqrtf(tY[base + 9]) - sqrtf(tH[base + 9]);
                coord += a * a + b2 * b2 + c1 * c1 + c2 * c2;
            }
        }

        // ---- slot phase: register accumulation, no atomics ----
        #pragma unroll
        for (int b = 0; b < 4; b++) {
            #pragma unroll
            for (int i = 0; i < 3; i++) {
                if (!val[i]) continue;
                const int cb = b * 1470 + ijv[i] * CC;
                const float w0 = (tY[cb] == 1.0f) ? 1.f : 0.f;
                const float w1 = (cv[i] >= 10 && tY[cb + 5] == 1.0f) ? 1.f : 0.f;
                const float t  = tY[cb + cv[i]];
                const float th = tH[cb + cv[i]];
                const float e  = __expf(th);
                const float te = t * e, ee = e * e, t2 = t * t;
                D0[i] = fmaf(e,  w0, D0[i]);
                B0[i] = fmaf(te, w0, B0[i]);
                C0[i] = fmaf(ee, w0, C0[i]);
                D1[i] = fmaf(e,  w1, D1[i]);
                B1[i] = fmaf(te, w1, B1[i]);
                C1[i] = fmaf(ee, w1, C1[i]);
                tt = fmaf(t2, w0 + w1, tt);
            }
        }
        __syncthreads();   // everyone done reading LDS
        if (s + 1 < nslab) {
            tY4[i0] = ry0; tY4[i1] = ry1; if (w2) tY4[i2] = ry2;
            tH4[i0] = rh0; tH4[i1] = rh1; if (w2) tH4[i2] = rh2;
        }
        __syncthreads();   // staged data visible
    }

    // ---- per-wg partials: contiguous block, coalesced stores ----
    float* pp = parts + (size_t)wg * PSTR;
    #pragma unroll
    for (int i = 0; i < 3; i++) {
        if (!val[i]) continue;
        const int p = pr[i];
        pp[p]            = D0[i];
        pp[NPAIR + p]    = B0[i];
        pp[2*NPAIR + p]  = C0[i];
        pp[3*NPAIR + p]  = D1[i];   // zero when cv<10 (w1 never set)
        pp[4*NPAIR + p]  = B1[i];
        pp[5*NPAIR + p]  = C1[i];
    }

    // ---- scalar sums: shuffle -> LDS -> one float4-worth store per wg ----
    const int lane = tid & 63, wv = tid >> 6;
    #pragma unroll
    for (int off = 32; off > 0; off >>= 1) {
        obj   += __shfl_down(obj,   off);
        noobj += __shfl_down(noobj, off);
        coord += __shfl_down(coord, off);
        tt    += __shfl_down(tt,    off);
    }
    if (lane == 0) { scr[0][wv] = obj; scr[1][wv] = noobj; scr[2][wv] = coord; scr[3][wv] = tt; }
    __syncthreads();
    if (tid < 4) {
        float sacc = 0.f;
        #pragma unroll
        for (int w = 0; w < THREADS / 64; w++) sacc += scr[tid][w];
        scal[wg * 4 + tid] = sacc;
    }
}

// grid (29, 8) x 512 threads: block (bx, cy) sums its 64 float4-slots over
// 1/8th of the wgs (8-way split inside the block), float4 loads, LDS fold,
// plain store into parts2[cy]. Fully deterministic.
__global__ __launch_bounds__(512)
void yolo_reduce(const float* __restrict__ parts, float* __restrict__ parts2, int nwg)
{
    const int lane = threadIdx.x & 63;          // float4 lane
    const int sub  = threadIdx.x >> 6;          // 0..7
    const int f4i  = blockIdx.x * 64 + lane;
    const int cy   = blockIdx.y;                // 0..7
    const int wpc  = nwg >> 3;                  // wgs per chunk
    const int wps  = wpc >> 3;                  // wgs per sub-group

    float4 s = make_float4(0.f, 0.f, 0.f, 0.f);
    if (f4i < PSTR / 4) {
        const float* q = parts + (size_t)(cy * wpc + sub * wps) * PSTR + f4i * 4;
        for (int w = 0; w < wps; ++w) {
            float4 a = *(const float4*)q;
            s.x += a.x; s.y += a.y; s.z += a.z; s.w += a.w;
            q += PSTR;
        }
    }
    __shared__ float4 sred[8][64];
    sred[sub][lane] = s;
    __syncthreads();
    if (threadIdx.x < 64 && f4i < PSTR / 4) {
        float4 t = sred[0][lane];
        #pragma unroll
        for (int c = 1; c < 8; c++) {
            float4 a = sred[c][lane];
            t.x += a.x; t.y += a.y; t.z += a.z; t.w += a.w;
        }
        *(float4*)(parts2 + (size_t)cy * PSTR + f4i * 4) = t;
    }
}

__global__ __launch_bounds__(1024)
void yolo_final(const float* __restrict__ parts2, const float* __restrict__ scal,
                float* __restrict__ out, int nwg)
{
    float v = 0.f;

    // prob term: fold the 8 chunk-partials, then per-slot contribution
    for (int s = threadIdx.x; s < NPAIR; s += 1024) {
        const int cidx = s % 25;
        float D0 = 0, B0 = 0, C0 = 0, D1 = 0, B1 = 0, C1 = 0;
        #pragma unroll
        for (int c = 0; c < 8; c++) {
            const float* t = parts2 + (size_t)c * PSTR;
            D0 += t[s];           B0 += t[NPAIR + s];   C0 += t[2*NPAIR + s];
            D1 += t[3*NPAIR + s]; B1 += t[4*NPAIR + s]; C1 += t[5*NPAIR + s];
        }
        if (D0 > 0.f) v += C0 / (D0 * D0) - 2.f * B0 / D0;
        if (cidx >= 5 && D1 > 0.f) v += C1 / (D1 * D1) - 2.f * B1 / D1;
    }

    // scalar terms: weights commute with the sum
    const float4* s4 = (const float4*)scal;
    for (int w = threadIdx.x; w < nwg; w += 1024) {
        float4 a = s4[w];
        v += a.x + 0.5f * a.y + 5.0f * a.z + a.w;
    }

    __shared__ float sred[16];
    #pragma unroll
    for (int off = 32; off > 0; off >>= 1) v += __shfl_down(v, off);
    const int lane = threadIdx.x & 63, wv = threadIdx.x >> 6;
    if (lane == 0) sred[wv] = v;
    __syncthreads();
    if (threadIdx.x == 0) {
        float tot = 0.f;
        #pragma unroll
        for (int w = 0; w < 16; w++) tot += sred[w];
        out[0] = tot / (float)NBATCH;
    }
}

extern "C" void kernel_launch(void* const* d_in, const int* in_sizes, int n_in,
                              void* d_out, int out_size, void* d_ws, size_t ws_size,
                              hipStream_t stream)
{
    const float* y  = (const float*)d_in[0];
    const float* yh = (const float*)d_in[1];
    float* out    = (float*)d_out;
    float* scal   = (float*)d_ws;
    float* parts2 = (float*)((char*)d_ws + 4096);
    float* parts  = (float*)((char*)d_ws + 239616);

    const size_t per_wg = (size_t)PSTR * sizeof(float);   // 29.4 KB
    int nwg;
    if      (ws_size >= 239616 + 256 * per_wg) nwg = 256;
    else if (ws_size >= 239616 + 128 * per_wg) nwg = 128;
    else                                       nwg = 64;

    yolo_main<<<nwg, THREADS, 0, stream>>>(y, yh, scal, parts, nwg);
    dim3 g2((PSTR / 4 + 63) / 64, 8);
    yolo_reduce<<<g2, 512, 0, stream>>>(parts, parts2, nwg);
    yolo_final<<<1, 1024, 0, stream>>>(parts2, scal, out, nwg);
}